// Round 7
// baseline (299.020 us; speedup 1.0000x reference)
//
#include <hip/hip_runtime.h>
#include <math.h>

#define NDF 11
#define MAXN 35

// ---------------------------------------------------------------------------
// k_prep: transpose hidden-layer weights to [o][k] f32, precompute BN consts,
// zero the fixup counter.
// ---------------------------------------------------------------------------
__global__ void k_prep(const float* __restrict__ nn1_w,
                       const float* __restrict__ nd1_w, const float* __restrict__ pd1_w,
                       const float* __restrict__ nd_g, const float* __restrict__ nd_be,
                       const float* __restrict__ nd_rm, const float* __restrict__ nd_rv,
                       const float* __restrict__ pd_g, const float* __restrict__ pd_be,
                       const float* __restrict__ pd_rm, const float* __restrict__ pd_rv,
                       float* __restrict__ w1t, float* __restrict__ nd1t,
                       float* __restrict__ pd1t, float* __restrict__ bnc,
                       int* __restrict__ cnt)
{
    const int i0 = blockIdx.x * 256 + threadIdx.x;   // 16 blocks
    if (i0 == 0) cnt[0] = 0;
    if (i0 < 64) {
        const float sc = nd_g[i0] / sqrtf(nd_rv[i0] + 1e-5f);
        bnc[i0]        = sc;
        bnc[64 + i0]   = nd_be[i0] - nd_rm[i0] * sc;
        const float sp = pd_g[i0] / sqrtf(pd_rv[i0] + 1e-5f);
        bnc[128 + i0]  = sp;
        bnc[192 + i0]  = pd_be[i0] - pd_rm[i0] * sp;
    }
    for (int i = i0; i < 64*64; i += 4096) {
        const int o = i >> 6, k = i & 63;
        const int src = k*64 + o;
        w1t[i]  = nn1_w[src];
        nd1t[i] = nd1_w[src];
        pd1t[i] = pd1_w[src];
    }
}

// ---------------------------------------------------------------------------
// k_mlp3: branch-split MLP. grid = 3 * (B/512); branch = blockIdx.x % 3
// (0 = num_nodes, 1 = node-feature head, 2 = position head).
// Each block: 256 threads x 2 graphs, stages s_lin + ONE 16KB matrix.
// 3072 waves total -> ~3 waves/SIMD (vs 1 for the monolithic version).
// ---------------------------------------------------------------------------
__global__ __launch_bounds__(256)
void k_mlp3(const float* __restrict__ z, const float* __restrict__ tpr,
            const float* __restrict__ lin_w, const float* __restrict__ lin_b,
            const float* __restrict__ w1t, const float* __restrict__ nn1_b,
            const float* __restrict__ nn2_w, const float* __restrict__ nn2_b,
            const float* __restrict__ nd1t, const float* __restrict__ nd1_b,
            const float* __restrict__ nd2_w, const float* __restrict__ nd2_b,
            const float* __restrict__ pd1t, const float* __restrict__ pd1_b,
            const float* __restrict__ pd2_w, const float* __restrict__ pd2_b,
            const float* __restrict__ bnc,
            const float* __restrict__ nsc, const float* __restrict__ nsh,
            const float* __restrict__ psc, const float* __restrict__ psh,
            float* __restrict__ nf_g, float* __restrict__ pos_g,
            int* __restrict__ nn_int, float* __restrict__ out_nn,
            int* __restrict__ flagged, int* __restrict__ cnt, int B)
{
    __shared__ __align__(16) float s_lin[33*64];   // 8448 B  [j][k]
    __shared__ __align__(16) float s_w[64*64];     // 16 KB   [o][k] (branch matrix)
    __shared__ __align__(16) float s_head[64*NDF]; // up to 2816 B (branch head)
    __shared__ float s_b1[64];                     // hidden-layer bias
    __shared__ float s_bnA[64], s_bnB[64];         // BN scale / bias (or w2 in s_bnA)
    __shared__ float s_hb[NDF];                    // head bias

    const int t = threadIdx.x;
    const int branch = blockIdx.x % 3;
    const int chunk  = blockIdx.x / 3;

    for (int i = t; i < 33*64; i += 256) s_lin[i] = lin_w[i];

    if (branch == 0) {
        for (int i = t; i < 64*64; i += 256) s_w[i] = w1t[i];
        if (t < 64) { s_b1[t] = nn1_b[t]; s_bnA[t] = nn2_w[t]; }
        if (t == 0) s_hb[0] = nn2_b[0];
    } else if (branch == 1) {
        for (int i = t; i < 64*64; i += 256) s_w[i] = nd1t[i];
        for (int i = t; i < 64*NDF; i += 256) s_head[i] = nd2_w[i];
        if (t < 64) { s_b1[t] = nd1_b[t]; s_bnA[t] = bnc[t]; s_bnB[t] = bnc[64 + t]; }
        if (t < NDF) s_hb[t] = nd2_b[t];
    } else {
        for (int i = t; i < 64*64; i += 256) s_w[i] = pd1t[i];
        if (t < 64*3) s_head[t] = pd2_w[t];
        if (t < 64) { s_b1[t] = pd1_b[t]; s_bnA[t] = bnc[128 + t]; s_bnB[t] = bnc[192 + t]; }
        if (t < 3) s_hb[t] = pd2_b[t];
    }
    __syncthreads();

    const int g0 = chunk * 512 + t;
    const int g1 = g0 + 256;
    if (g0 >= B) return;

    const float tpA = tpr[g0];
    const float tpB = tpr[g1];

    // ---- phase A: h = concat(z, tp) @ lin_w + lin_b (both graphs) ----
    float hA[64], hB[64];
    #pragma unroll
    for (int k = 0; k < 64; k++) { hA[k] = s_lin[0]; }  // placeholder overwritten below
    {
        const float* lb = lin_b;   // wave-uniform global (small, L2) -> cheap
        #pragma unroll
        for (int k = 0; k < 64; k++) { hA[k] = lb[k]; hB[k] = hA[k]; }
    }

    #pragma unroll 1
    for (int j = 0; j < 33; j++) {
        const float xA = (j < 32) ? z[(size_t)g0*32 + j] : tpA;
        const float xB = (j < 32) ? z[(size_t)g1*32 + j] : tpB;
        const float4* row = (const float4*)(s_lin + j*64);
        #pragma unroll
        for (int m = 0; m < 16; m++) {
            const float4 w = row[m];
            hA[4*m+0] = fmaf(xA, w.x, hA[4*m+0]);
            hA[4*m+1] = fmaf(xA, w.y, hA[4*m+1]);
            hA[4*m+2] = fmaf(xA, w.z, hA[4*m+2]);
            hA[4*m+3] = fmaf(xA, w.w, hA[4*m+3]);
            hB[4*m+0] = fmaf(xB, w.x, hB[4*m+0]);
            hB[4*m+1] = fmaf(xB, w.y, hB[4*m+1]);
            hB[4*m+2] = fmaf(xB, w.z, hB[4*m+2]);
            hB[4*m+3] = fmaf(xB, w.w, hB[4*m+3]);
        }
    }

    // ---- branch-specific hidden layer + head ----
    if (branch == 0) {
        float lgA = s_hb[0], lgB = s_hb[0];
        #pragma unroll 1
        for (int o = 0; o < 64; o++) {
            const float4* c = (const float4*)(s_w + o*64);
            float a0 = s_b1[o], a1 = 0.f, b0 = s_b1[o], b1 = 0.f;
            #pragma unroll
            for (int m = 0; m < 16; m++) {
                const float4 w = c[m];
                a0 = fmaf(hA[4*m+0], w.x, a0); a1 = fmaf(hA[4*m+1], w.y, a1);
                a0 = fmaf(hA[4*m+2], w.z, a0); a1 = fmaf(hA[4*m+3], w.w, a1);
                b0 = fmaf(hB[4*m+0], w.x, b0); b1 = fmaf(hB[4*m+1], w.y, b1);
                b0 = fmaf(hB[4*m+2], w.z, b0); b1 = fmaf(hB[4*m+3], w.w, b1);
            }
            const float w2o = s_bnA[o];
            const float aA = a0 + a1; if (aA > 0.f) lgA = fmaf(aA, w2o, lgA);
            const float aB = b0 + b1; if (aB > 0.f) lgB = fmaf(aB, w2o, lgB);
        }
        const float argA = fmaf(1.f / (1.f + expf(-lgA)), 30.f, 5.f);
        const float argB = fmaf(1.f / (1.f + expf(-lgB)), 30.f, 5.f);
        const int nA = (int)argA;
        const int nB = (int)argB;
        nn_int[g0] = nA;  out_nn[g0] = (float)nA;
        nn_int[g1] = nB;  out_nn[g1] = (float)nB;
        if (fabsf(argA - rintf(argA)) < 0.02f) { const int i = atomicAdd(cnt, 1); flagged[i] = g0; }
        if (fabsf(argB - rintf(argB)) < 0.02f) { const int i = atomicAdd(cnt, 1); flagged[i] = g1; }
    } else if (branch == 1) {
        float nfA[NDF], nfB[NDF];
        #pragma unroll
        for (int j = 0; j < NDF; j++) { nfA[j] = s_hb[j]; nfB[j] = s_hb[j]; }
        #pragma unroll 1
        for (int o = 0; o < 64; o++) {
            const float4* c = (const float4*)(s_w + o*64);
            float a0 = s_b1[o], a1 = 0.f, b0 = s_b1[o], b1 = 0.f;
            #pragma unroll
            for (int m = 0; m < 16; m++) {
                const float4 w = c[m];
                a0 = fmaf(hA[4*m+0], w.x, a0); a1 = fmaf(hA[4*m+1], w.y, a1);
                a0 = fmaf(hA[4*m+2], w.z, a0); a1 = fmaf(hA[4*m+3], w.w, a1);
                b0 = fmaf(hB[4*m+0], w.x, b0); b1 = fmaf(hB[4*m+1], w.y, b1);
                b0 = fmaf(hB[4*m+2], w.z, b0); b1 = fmaf(hB[4*m+3], w.w, b1);
            }
            float rA = a0 + a1; rA = rA > 0.f ? rA : 0.f;
            float rB = b0 + b1; rB = rB > 0.f ? rB : 0.f;
            const float tA = fmaf(rA, s_bnA[o], s_bnB[o]);
            const float tB = fmaf(rB, s_bnA[o], s_bnB[o]);
            #pragma unroll
            for (int j = 0; j < NDF; j++) {
                const float w = s_head[o*NDF + j];
                nfA[j] = fmaf(tA, w, nfA[j]);
                nfB[j] = fmaf(tB, w, nfB[j]);
            }
        }
        const float a_ns = nsc[0], a_nh = nsh[0];
        #pragma unroll
        for (int j = 0; j < NDF; j++) {
            nf_g[(size_t)g0*NDF + j] = fmaf(nfA[j], a_ns, a_nh);
            nf_g[(size_t)g1*NDF + j] = fmaf(nfB[j], a_ns, a_nh);
        }
    } else {
        float pxA = s_hb[0], pyA = s_hb[1], pzA = s_hb[2];
        float pxB = s_hb[0], pyB = s_hb[1], pzB = s_hb[2];
        #pragma unroll 1
        for (int o = 0; o < 64; o++) {
            const float4* c = (const float4*)(s_w + o*64);
            float a0 = s_b1[o], a1 = 0.f, b0 = s_b1[o], b1 = 0.f;
            #pragma unroll
            for (int m = 0; m < 16; m++) {
                const float4 w = c[m];
                a0 = fmaf(hA[4*m+0], w.x, a0); a1 = fmaf(hA[4*m+1], w.y, a1);
                a0 = fmaf(hA[4*m+2], w.z, a0); a1 = fmaf(hA[4*m+3], w.w, a1);
                b0 = fmaf(hB[4*m+0], w.x, b0); b1 = fmaf(hB[4*m+1], w.y, b1);
                b0 = fmaf(hB[4*m+2], w.z, b0); b1 = fmaf(hB[4*m+3], w.w, b1);
            }
            float rA = a0 + a1; rA = rA > 0.f ? rA : 0.f;
            float rB = b0 + b1; rB = rB > 0.f ? rB : 0.f;
            const float tA = fmaf(rA, s_bnA[o], s_bnB[o]);
            const float tB = fmaf(rB, s_bnA[o], s_bnB[o]);
            const float q0 = s_head[o*3+0], q1 = s_head[o*3+1], q2 = s_head[o*3+2];
            pxA = fmaf(tA, q0, pxA); pyA = fmaf(tA, q1, pyA); pzA = fmaf(tA, q2, pzA);
            pxB = fmaf(tB, q0, pxB); pyB = fmaf(tB, q1, pyB); pzB = fmaf(tB, q2, pzB);
        }
        const float a_ps = psc[0], a_ph = psh[0];
        pos_g[(size_t)g0*3+0] = fmaf(pxA, a_ps, a_ph);
        pos_g[(size_t)g0*3+1] = fmaf(pyA, a_ps, a_ph);
        pos_g[(size_t)g0*3+2] = fmaf(pzA, a_ps, a_ph);
        pos_g[(size_t)g1*3+0] = fmaf(pxB, a_ps, a_ph);
        pos_g[(size_t)g1*3+1] = fmaf(pyB, a_ps, a_ph);
        pos_g[(size_t)g1*3+2] = fmaf(pzB, a_ps, a_ph);
    }
}

// ---------------------------------------------------------------------------
// k_fix: f64 re-derivation of num_nodes for flagged graphs. One WAVE per
// graph: lane k computes h_k (f64), shuffle-broadcast for nn1, butterfly
// reduce for the logit.
// ---------------------------------------------------------------------------
__global__ __launch_bounds__(256)
void k_fix(const float* __restrict__ z, const float* __restrict__ tpr,
           const float* __restrict__ lin_w, const float* __restrict__ lin_b,
           const float* __restrict__ nn1_w, const float* __restrict__ nn1_b,
           const float* __restrict__ nn2_w, const float* __restrict__ nn2_b,
           const int* __restrict__ flagged, const int* __restrict__ cnt,
           int* __restrict__ nn_int, float* __restrict__ out_nn)
{
    const int count = cnt[0];
    const int lane = threadIdx.x & 63;
    const int wv = (blockIdx.x * 256 + threadIdx.x) >> 6;   // 2048 waves
    const double b2 = (double)nn2_b[0];

    for (int w = wv; w < count; w += 2048) {
        const int g = flagged[w];

        double hk = (double)lin_b[lane];
        for (int j = 0; j < 32; j++)
            hk = fma((double)z[(size_t)g*32 + j], (double)lin_w[j*64 + lane], hk);
        hk = fma((double)tpr[g], (double)lin_w[32*64 + lane], hk);

        double a = (double)nn1_b[lane];
        for (int k = 0; k < 64; k++) {
            const double hks = __shfl(hk, k);
            a = fma(hks, (double)nn1_w[k*64 + lane], a);
        }
        double v = (a > 0.0) ? a * (double)nn2_w[lane] : 0.0;
        for (int d = 32; d > 0; d >>= 1) v += __shfl_xor(v, d);
        const double logit = v + b2;

        if (lane == 0) {
            const double sg = 1.0 / (1.0 + exp(-logit));
            const int n = (int)(sg * 30.0 + 5.0);
            nn_int[g] = n;
            out_nn[g] = (float)n;
        }
    }
}

// ---------------------------------------------------------------------------
// 3-kernel inclusive prefix sum over B elements (B = nb*256).
// ---------------------------------------------------------------------------
__global__ __launch_bounds__(256)
void k_scan1(const int* __restrict__ a, int* __restrict__ part, int* __restrict__ bsum)
{
    __shared__ int s[256];
    const int t = threadIdx.x;
    const int g = blockIdx.x * 256 + t;
    const int v = a[g];
    s[t] = v;
    __syncthreads();
    for (int d = 1; d < 256; d <<= 1) {
        const int x = s[t];
        const int add = (t >= d) ? s[t - d] : 0;
        __syncthreads();
        s[t] = x + add;
        __syncthreads();
    }
    part[g] = s[t];
    if (t == 255) bsum[blockIdx.x] = s[255];
}

__global__ void k_scan2(const int* __restrict__ bsum, int* __restrict__ boff, int nb)
{
    __shared__ int s[1024];
    const int t = threadIdx.x;     // launched with nb threads (nb = 512, pow2)
    const int v = bsum[t];
    s[t] = v;
    __syncthreads();
    for (int d = 1; d < nb; d <<= 1) {
        const int x = s[t];
        const int add = (t >= d) ? s[t - d] : 0;
        __syncthreads();
        s[t] = x + add;
        __syncthreads();
    }
    boff[t] = s[t] - v;            // exclusive
}

__global__ __launch_bounds__(256)
void k_scan3(const int* __restrict__ part, const int* __restrict__ boff, int* __restrict__ C)
{
    const int g = blockIdx.x * 256 + threadIdx.x;
    C[g] = part[g] + boff[blockIdx.x];
}

// ---------------------------------------------------------------------------
// k_expand: 2 rows/thread, rows packed in LDS, fully-coalesced float4 stores.
// Rows >= C[B-1] repeat graph B-1 (JAX total_repeat_length padding).
// ---------------------------------------------------------------------------
__global__ __launch_bounds__(256)
void k_expand(const int* __restrict__ C, const float* __restrict__ nf_g,
              const float* __restrict__ pos_g, float* __restrict__ out,
              int B, int T)
{
    __shared__ __align__(16) float s_nf[512*NDF];   // 22528 B
    __shared__ __align__(16) float s_ps[512*3];     // 6144 B
    const int t = threadIdx.x;
    const int r0 = blockIdx.x * 512 + 2*t;

    int lo = 0, hi = B;
    while (lo < hi) {
        const int m = (lo + hi) >> 1;
        if (C[m] <= r0) lo = m + 1; else hi = m;
    }
    const int i0 = lo < B ? lo : B - 1;
    const int i1 = ((r0 + 1) >= C[i0] && i0 < B - 1) ? i0 + 1 : i0;

    #pragma unroll
    for (int j = 0; j < NDF; j++) {
        s_nf[(2*t)*NDF + j]     = nf_g[(size_t)i0*NDF + j];
        s_nf[(2*t + 1)*NDF + j] = nf_g[(size_t)i1*NDF + j];
    }
    #pragma unroll
    for (int j = 0; j < 3; j++) {
        s_ps[(2*t)*3 + j]     = pos_g[(size_t)i0*3 + j];
        s_ps[(2*t + 1)*3 + j] = pos_g[(size_t)i1*3 + j];
    }
    __syncthreads();

    float4* onf = (float4*)(out + (size_t)blockIdx.x * 512 * NDF);
    const float4* snf = (const float4*)s_nf;
    #pragma unroll
    for (int q = 0; q < 6; q++) {
        const int idx = q*256 + t;
        if (idx < 512*NDF/4) onf[idx] = snf[idx];    // 1408 float4
    }
    float4* ops = (float4*)(out + (size_t)T*NDF + (size_t)blockIdx.x * 512 * 3);
    const float4* sps = (const float4*)s_ps;
    #pragma unroll
    for (int q = 0; q < 2; q++) {
        const int idx = q*256 + t;
        if (idx < 384) ops[idx] = sps[idx];          // 384 float4
    }
}

// ---------------------------------------------------------------------------
extern "C" void kernel_launch(void* const* d_in, const int* in_sizes, int n_in,
                              void* d_out, int out_size, void* d_ws, size_t ws_size,
                              hipStream_t stream)
{
    const float* z     = (const float*)d_in[0];
    const float* tpr   = (const float*)d_in[1];
    const int    B     = in_sizes[1];          // target_property length
    const int    T     = B * MAXN;

    const float* lin_w = (const float*)d_in[3];
    const float* lin_b = (const float*)d_in[4];
    const float* nn1_w = (const float*)d_in[5];
    const float* nn1_b = (const float*)d_in[6];
    const float* nn2_w = (const float*)d_in[7];
    const float* nn2_b = (const float*)d_in[8];
    const float* nd1_w = (const float*)d_in[9];
    const float* nd1_b = (const float*)d_in[10];
    const float* nd_g  = (const float*)d_in[11];
    const float* nd_be = (const float*)d_in[12];
    const float* nd_rm = (const float*)d_in[13];
    const float* nd_rv = (const float*)d_in[14];
    const float* nd2_w = (const float*)d_in[15];
    const float* nd2_b = (const float*)d_in[16];
    const float* pd1_w = (const float*)d_in[17];
    const float* pd1_b = (const float*)d_in[18];
    const float* pd_g  = (const float*)d_in[19];
    const float* pd_be = (const float*)d_in[20];
    const float* pd_rm = (const float*)d_in[21];
    const float* pd_rv = (const float*)d_in[22];
    const float* pd2_w = (const float*)d_in[23];
    const float* pd2_b = (const float*)d_in[24];
    const float* nsc   = (const float*)d_in[25];
    const float* nsh   = (const float*)d_in[26];
    const float* psc   = (const float*)d_in[27];
    const float* psh   = (const float*)d_in[28];

    float* out = (float*)d_out;

    // workspace layout (256B-aligned slices)
    char* w = (char*)d_ws;
    size_t off = 0;
    auto take = [&](size_t bytes) { void* p = w + off; off = (off + bytes + 255) & ~(size_t)255; return p; };

    float* w1t   = (float*)take(64*64*sizeof(float));
    float* nd1t  = (float*)take(64*64*sizeof(float));
    float* pd1t  = (float*)take(64*64*sizeof(float));
    float* bnc   = (float*)take(256*sizeof(float));
    int*   cnt   = (int*)take(256);
    float* nf_g  = (float*)take((size_t)B*NDF*sizeof(float));
    float* pos_g = (float*)take((size_t)B*3*sizeof(float));
    int*   nn_i  = (int*)take((size_t)B*sizeof(int));
    int*   part  = (int*)take((size_t)B*sizeof(int));
    int*   bsum  = (int*)take(4096*sizeof(int));
    int*   boff  = (int*)take(4096*sizeof(int));
    int*   C     = (int*)take((size_t)B*sizeof(int));
    int*   flagged = C;   // alias: flagged is consumed by k_fix BEFORE scan3 writes C

    const int nb = B / 256;   // 512 for B=131072

    k_prep<<<16, 256, 0, stream>>>(nn1_w, nd1_w, pd1_w,
                                   nd_g, nd_be, nd_rm, nd_rv,
                                   pd_g, pd_be, pd_rm, pd_rv,
                                   w1t, nd1t, pd1t, bnc, cnt);

    k_mlp3<<<3*(B/512), 256, 0, stream>>>(z, tpr, lin_w, lin_b,
                                          w1t, nn1_b, nn2_w, nn2_b,
                                          nd1t, nd1_b, nd2_w, nd2_b,
                                          pd1t, pd1_b, pd2_w, pd2_b, bnc,
                                          nsc, nsh, psc, psh,
                                          nf_g, pos_g, nn_i, out + (size_t)T*14,
                                          flagged, cnt, B);

    k_fix<<<512, 256, 0, stream>>>(z, tpr, lin_w, lin_b, nn1_w, nn1_b, nn2_w, nn2_b,
                                   flagged, cnt, nn_i, out + (size_t)T*14);

    k_scan1<<<nb, 256, 0, stream>>>(nn_i, part, bsum);
    k_scan2<<<1, nb, 0, stream>>>(bsum, boff, nb);
    k_scan3<<<nb, 256, 0, stream>>>(part, boff, C);

    k_expand<<<T/512, 256, 0, stream>>>(C, nf_g, pos_g, out, B, T);

    (void)n_in; (void)out_size; (void)ws_size;
}

// Round 8
// 257.424 us; speedup vs baseline: 1.1616x; 1.1616x over previous
//
#include <hip/hip_runtime.h>
#include <math.h>

typedef unsigned int u32;
typedef unsigned short u16;
typedef __attribute__((ext_vector_type(8))) short short8v;   // 8 bf16 = 4 VGPR
typedef __attribute__((ext_vector_type(4))) float f32x4;

#define NDF 11
#define MAXN 35
#define RS 72          // padded LDS row stride in bf16 elems (144 B, 16B-aligned, conflict-safe)

__device__ __forceinline__ u16 f2bf(float x) {
    u32 b = __float_as_uint(x);
    u32 r = (b + 0x7fffu + ((b >> 16) & 1u)) >> 16;
    return (u16)r;
}
__device__ __forceinline__ float bf2f(u16 h) {
    return __uint_as_float(((u32)h) << 16);
}
__device__ __forceinline__ void splitbf(float x, u16& hi, u16& lo) {
    hi = f2bf(x);
    lo = f2bf(x - bf2f(hi));
}

// ---------------------------------------------------------------------------
// k_prep: build transposed, padded, split-bf16 weight images in ws + BN consts.
//   lint  [2][64][RS]  : lin^T   (n = h-index, k = input j; j>=33 -> 0)
//   w1t3  [3][2][64][RS]: {nn1,nd1,pd1}^T  (n = o, k = h-index)
//   w2t3  [3][2][16][RS]: head^T slices (n = out col, k = o)
//         b0: n==14 -> nn2_w[k]; b1: n<11 -> nd2_w[k][n]; b2: n in 11..13 -> pd2_w[k][n-11]
// ---------------------------------------------------------------------------
__global__ void k_prep(const float* __restrict__ lin_w,
                       const float* __restrict__ nn1_w, const float* __restrict__ nn2_w,
                       const float* __restrict__ nd1_w, const float* __restrict__ nd2_w,
                       const float* __restrict__ pd1_w, const float* __restrict__ pd2_w,
                       const float* __restrict__ nd_g, const float* __restrict__ nd_be,
                       const float* __restrict__ nd_rm, const float* __restrict__ nd_rv,
                       const float* __restrict__ pd_g, const float* __restrict__ pd_be,
                       const float* __restrict__ pd_rm, const float* __restrict__ pd_rv,
                       u16* __restrict__ lint, u16* __restrict__ w1t3,
                       u16* __restrict__ w2t3, float* __restrict__ bnc,
                       int* __restrict__ cnt)
{
    const int t0 = blockIdx.x * 256 + threadIdx.x;     // 16 blocks -> 4096
    if (t0 == 0) cnt[0] = 0;
    if (t0 < 64) {
        const float sc = nd_g[t0] / sqrtf(nd_rv[t0] + 1e-5f);
        bnc[t0]       = sc;
        bnc[64 + t0]  = nd_be[t0] - nd_rm[t0] * sc;
        const float sp = pd_g[t0] / sqrtf(pd_rv[t0] + 1e-5f);
        bnc[128 + t0] = sp;
        bnc[192 + t0] = pd_be[t0] - pd_rm[t0] * sp;
    }
    for (int i = t0; i < 64*RS; i += 4096) {
        const int n = i / RS, k = i % RS;
        const float v = (k < 33) ? lin_w[k*64 + n] : 0.f;
        u16 h, l; splitbf(v, h, l);
        lint[i] = h; lint[64*RS + i] = l;
    }
    for (int b = 0; b < 3; b++) {
        const float* M = (b == 0) ? nn1_w : (b == 1) ? nd1_w : pd1_w;
        u16* dst = w1t3 + (size_t)b * 2 * 64 * RS;
        for (int i = t0; i < 64*RS; i += 4096) {
            const int o = i / RS, k = i % RS;
            const float v = (k < 64) ? M[k*64 + o] : 0.f;
            u16 h, l; splitbf(v, h, l);
            dst[i] = h; dst[64*RS + i] = l;
        }
        u16* d2 = w2t3 + (size_t)b * 2 * 16 * RS;
        for (int i = t0; i < 16*RS; i += 4096) {
            const int n = i / RS, k = i % RS;
            float v = 0.f;
            if (k < 64) {
                if (b == 0)      { if (n == 14)           v = nn2_w[k]; }
                else if (b == 1) { if (n < 11)            v = nd2_w[k*11 + n]; }
                else             { if (n >= 11 && n < 14) v = pd2_w[k*3 + (n-11)]; }
            }
            u16 h, l; splitbf(v, h, l);
            d2[i] = h; d2[16*RS + i] = l;
        }
    }
}

// ---------------------------------------------------------------------------
// k_mfma: 64 graphs per block, 256 threads = 4 waves (one 16-row M-band each).
// GEMM chain via mfma_f32_16x16x32_bf16 with split-bf16 (hi/lo) operands:
//   X[64][64] @ lin -> H ; H @ {nn1|nd1|pd1} -> T (relu/BN) ; T @ head -> C2[.,16]
// C/D layout (HW-verified): col=lane&15, row=(lane>>4)*4+reg.
// A/B k-slots use one consistent bijection (k = ks*32 + (lane>>4)*8 + j) for
// both operands -> sum is layout-independent.
// ---------------------------------------------------------------------------
__global__ __launch_bounds__(256)
void k_mfma(const float* __restrict__ z, const float* __restrict__ tpr,
            const float* __restrict__ lin_b,
            const u16* __restrict__ lint, const u16* __restrict__ w1t3,
            const u16* __restrict__ w2t3,
            const float* __restrict__ nn1_b, const float* __restrict__ nd1_b,
            const float* __restrict__ pd1_b,
            const float* __restrict__ nn2_b, const float* __restrict__ nd2_b,
            const float* __restrict__ pd2_b,
            const float* __restrict__ bnc,
            const float* __restrict__ nsc, const float* __restrict__ nsh,
            const float* __restrict__ psc, const float* __restrict__ psh,
            float* __restrict__ nf_g, float* __restrict__ pos_g,
            int* __restrict__ nn_int, float* __restrict__ out_nn,
            int* __restrict__ flagged, int* __restrict__ cnt, int B)
{
    __shared__ __align__(16) u16 sA[2*64*RS];    // X, later T   (hi | lo)
    __shared__ __align__(16) u16 sH[2*64*RS];    // H            (hi | lo)
    __shared__ __align__(16) u16 sW[2*64*RS];    // lin^T, later branch matrix^T
    __shared__ __align__(16) u16 sW2[2*16*RS];   // head slice^T
    __shared__ float s_linb[64], s_b1[64], s_sc[64], s_bi[64];

    const int t    = threadIdx.x;
    const int lane = t & 63;
    const int w    = t >> 6;
    const int g_lo = blockIdx.x * 64;

    // ---- stage X (split bf16) + lin^T + lin bias ----
    {
        const float4* zb = (const float4*)(z + (size_t)g_lo * 32);
        const float4 v0 = zb[2*t], v1 = zb[2*t + 1];
        const float xv[8] = {v0.x, v0.y, v0.z, v0.w, v1.x, v1.y, v1.z, v1.w};
        const int g  = t >> 2;
        const int j0 = (t & 3) * 8;
        u16 hs[8], ls[8];
        #pragma unroll
        for (int i = 0; i < 8; i++) splitbf(xv[i], hs[i], ls[i]);
        u32* hp = (u32*)(sA + g*RS + j0);
        u32* lp = (u32*)(sA + 64*RS + g*RS + j0);
        #pragma unroll
        for (int q = 0; q < 4; q++) {
            hp[q] = (u32)hs[2*q] | ((u32)hs[2*q+1] << 16);
            lp[q] = (u32)ls[2*q] | ((u32)ls[2*q+1] << 16);
        }
        if (t < 64) {
            u16 h, l; splitbf(tpr[g_lo + t], h, l);
            sA[t*RS + 32] = h;  sA[64*RS + t*RS + 32] = l;
            sA[t*RS + 33] = 0;  sA[64*RS + t*RS + 33] = 0;
            u32* zp = (u32*)(sA + t*RS + 34);
            u32* zq = (u32*)(sA + 64*RS + t*RS + 34);
            #pragma unroll
            for (int q = 0; q < 19; q++) { zp[q] = 0; zq[q] = 0; }
            s_linb[t] = lin_b[t];
        }
        const uint4* src = (const uint4*)lint;
        uint4* dst = (uint4*)sW;
        for (int i = t; i < 2*64*RS/8; i += 256) dst[i] = src[i];
    }
    __syncthreads();

    auto ldfrag = [&](const u16* base, int row0, int ks) -> short8v {
        const uint4 v = *(const uint4*)(base + (row0 + (lane & 15))*RS + ks*32 + ((lane >> 4) * 8));
        return __builtin_bit_cast(short8v, v);
    };
    // 2 k-steps x {hi*hi, hi*lo, lo*hi}
    auto gemm6 = [&](const u16* Ahi, const u16* Bhi, const u16* Blo,
                     int arow0, int brow0, f32x4 acc) -> f32x4 {
        #pragma unroll
        for (int ks = 0; ks < 2; ks++) {
            const short8v ah = ldfrag(Ahi,          arow0, ks);
            const short8v al = ldfrag(Ahi + 64*RS,  arow0, ks);
            const short8v bh = ldfrag(Bhi,          brow0, ks);
            const short8v bl = ldfrag(Blo,          brow0, ks);
            acc = __builtin_amdgcn_mfma_f32_16x16x32_bf16(ah, bh, acc, 0, 0, 0);
            acc = __builtin_amdgcn_mfma_f32_16x16x32_bf16(ah, bl, acc, 0, 0, 0);
            acc = __builtin_amdgcn_mfma_f32_16x16x32_bf16(al, bh, acc, 0, 0, 0);
        }
        return acc;
    };

    const int arow0 = w * 16;

    // ---- phase A: H = X @ lin + lin_b ----
    #pragma unroll 1
    for (int nt = 0; nt < 4; nt++) {
        f32x4 acc = {0.f, 0.f, 0.f, 0.f};
        acc = gemm6(sA, sW, sW + 64*RS, arow0, nt*16, acc);
        const int col = nt*16 + (lane & 15);
        const float bias = s_linb[col];
        #pragma unroll
        for (int r = 0; r < 4; r++) {
            const int row = arow0 + (lane >> 4)*4 + r;
            u16 h, l; splitbf(acc[r] + bias, h, l);
            sH[row*RS + col] = h;
            sH[64*RS + row*RS + col] = l;
        }
    }
    __syncthreads();

    // ---- branches: stage1 (hidden+act) -> T, stage2 (head) accumulates C2 ----
    f32x4 acc2 = {0.f, 0.f, 0.f, 0.f};
    #pragma unroll 1
    for (int b = 0; b < 3; b++) {
        {
            const uint4* src = (const uint4*)(w1t3 + (size_t)b * 2 * 64 * RS);
            uint4* dst = (uint4*)sW;
            for (int i = t; i < 2*64*RS/8; i += 256) dst[i] = src[i];
            const uint4* s2 = (const uint4*)(w2t3 + (size_t)b * 2 * 16 * RS);
            uint4* d2 = (uint4*)sW2;
            for (int i = t; i < 2*16*RS/8; i += 256) d2[i] = s2[i];
            if (t < 64) {
                s_b1[t] = (b == 0) ? nn1_b[t] : (b == 1) ? nd1_b[t] : pd1_b[t];
                if (b == 1)      { s_sc[t] = bnc[t];       s_bi[t] = bnc[64 + t]; }
                else if (b == 2) { s_sc[t] = bnc[128 + t]; s_bi[t] = bnc[192 + t]; }
            }
        }
        __syncthreads();

        #pragma unroll 1
        for (int nt = 0; nt < 4; nt++) {
            f32x4 acc = {0.f, 0.f, 0.f, 0.f};
            acc = gemm6(sH, sW, sW + 64*RS, arow0, nt*16, acc);
            const int col = nt*16 + (lane & 15);
            const float b1 = s_b1[col];
            const float sc = s_sc[col];
            const float bi = s_bi[col];
            #pragma unroll
            for (int r = 0; r < 4; r++) {
                const int row = arow0 + (lane >> 4)*4 + r;
                float rv = acc[r] + b1;
                rv = rv > 0.f ? rv : 0.f;
                const float tv = (b == 0) ? rv : fmaf(rv, sc, bi);
                u16 h, l; splitbf(tv, h, l);
                sA[row*RS + col] = h;
                sA[64*RS + row*RS + col] = l;
            }
        }
        __syncthreads();

        acc2 = gemm6(sA, sW2, sW2 + 16*RS, arow0, 0, acc2);
        __syncthreads();
    }

    // ---- epilogue: C2 cols 0-10 = nf, 11-13 = pos, 14 = logit ----
    {
        const int col = lane & 15;
        const float nsc0 = nsc[0], nsh0 = nsh[0], psc0 = psc[0], psh0 = psh[0];
        #pragma unroll
        for (int r = 0; r < 4; r++) {
            const int row = arow0 + (lane >> 4)*4 + r;
            const int g = g_lo + row;
            const float v = acc2[r];
            if (col < 11) {
                nf_g[(size_t)g*NDF + col] = fmaf(v + nd2_b[col], nsc0, nsh0);
            } else if (col < 14) {
                pos_g[(size_t)g*3 + (col - 11)] = fmaf(v + pd2_b[col - 11], psc0, psh0);
            } else if (col == 14) {
                const float logit = v + nn2_b[0];
                const float arg = fmaf(1.f / (1.f + expf(-logit)), 30.f, 5.f);
                const int n = (int)arg;
                nn_int[g] = n;
                out_nn[g] = (float)n;
                if (fabsf(arg - rintf(arg)) < 0.05f) {
                    const int i = atomicAdd(cnt, 1);
                    flagged[i] = g;
                }
            }
        }
    }
    (void)B;
}

// ---------------------------------------------------------------------------
// k_fix: exact f64 re-derivation of num_nodes for flagged graphs (one wave
// per graph; lane k computes h_k, shuffle-broadcast, butterfly reduce).
// ---------------------------------------------------------------------------
__global__ __launch_bounds__(256)
void k_fix(const float* __restrict__ z, const float* __restrict__ tpr,
           const float* __restrict__ lin_w, const float* __restrict__ lin_b,
           const float* __restrict__ nn1_w, const float* __restrict__ nn1_b,
           const float* __restrict__ nn2_w, const float* __restrict__ nn2_b,
           const int* __restrict__ flagged, const int* __restrict__ cnt,
           int* __restrict__ nn_int, float* __restrict__ out_nn)
{
    const int count = cnt[0];
    const int lane = threadIdx.x & 63;
    const int wv = (blockIdx.x * 256 + threadIdx.x) >> 6;   // 2048 waves
    const double b2 = (double)nn2_b[0];

    for (int w = wv; w < count; w += 2048) {
        const int g = flagged[w];

        double hk = (double)lin_b[lane];
        for (int j = 0; j < 32; j++)
            hk = fma((double)z[(size_t)g*32 + j], (double)lin_w[j*64 + lane], hk);
        hk = fma((double)tpr[g], (double)lin_w[32*64 + lane], hk);

        double a = (double)nn1_b[lane];
        for (int k = 0; k < 64; k++) {
            const double hks = __shfl(hk, k);
            a = fma(hks, (double)nn1_w[k*64 + lane], a);
        }
        double v = (a > 0.0) ? a * (double)nn2_w[lane] : 0.0;
        for (int d = 32; d > 0; d >>= 1) v += __shfl_xor(v, d);
        const double logit = v + b2;

        if (lane == 0) {
            const double sg = 1.0 / (1.0 + exp(-logit));
            const int n = (int)(sg * 30.0 + 5.0);
            nn_int[g] = n;
            out_nn[g] = (float)n;
        }
    }
}

// ---------------------------------------------------------------------------
// 3-kernel inclusive prefix sum over B elements (B = nb*256).
// ---------------------------------------------------------------------------
__global__ __launch_bounds__(256)
void k_scan1(const int* __restrict__ a, int* __restrict__ part, int* __restrict__ bsum)
{
    __shared__ int s[256];
    const int t = threadIdx.x;
    const int g = blockIdx.x * 256 + t;
    const int v = a[g];
    s[t] = v;
    __syncthreads();
    for (int d = 1; d < 256; d <<= 1) {
        const int x = s[t];
        const int add = (t >= d) ? s[t - d] : 0;
        __syncthreads();
        s[t] = x + add;
        __syncthreads();
    }
    part[g] = s[t];
    if (t == 255) bsum[blockIdx.x] = s[255];
}

__global__ void k_scan2(const int* __restrict__ bsum, int* __restrict__ boff, int nb)
{
    __shared__ int s[1024];
    const int t = threadIdx.x;     // nb threads (512, pow2)
    const int v = bsum[t];
    s[t] = v;
    __syncthreads();
    for (int d = 1; d < nb; d <<= 1) {
        const int x = s[t];
        const int add = (t >= d) ? s[t - d] : 0;
        __syncthreads();
        s[t] = x + add;
        __syncthreads();
    }
    boff[t] = s[t] - v;            // exclusive
}

__global__ __launch_bounds__(256)
void k_scan3(const int* __restrict__ part, const int* __restrict__ boff, int* __restrict__ C)
{
    const int g = blockIdx.x * 256 + threadIdx.x;
    C[g] = part[g] + boff[blockIdx.x];
}

// ---------------------------------------------------------------------------
// k_expand: 2 rows/thread, rows packed in LDS, coalesced float4 stores.
// Rows >= C[B-1] repeat graph B-1 (JAX total_repeat_length padding).
// ---------------------------------------------------------------------------
__global__ __launch_bounds__(256)
void k_expand(const int* __restrict__ C, const float* __restrict__ nf_g,
              const float* __restrict__ pos_g, float* __restrict__ out,
              int B, int T)
{
    __shared__ __align__(16) float s_nf[512*NDF];
    __shared__ __align__(16) float s_ps[512*3];
    const int t = threadIdx.x;
    const int r0 = blockIdx.x * 512 + 2*t;

    int lo = 0, hi = B;
    while (lo < hi) {
        const int m = (lo + hi) >> 1;
        if (C[m] <= r0) lo = m + 1; else hi = m;
    }
    const int i0 = lo < B ? lo : B - 1;
    const int i1 = ((r0 + 1) >= C[i0] && i0 < B - 1) ? i0 + 1 : i0;

    #pragma unroll
    for (int j = 0; j < NDF; j++) {
        s_nf[(2*t)*NDF + j]     = nf_g[(size_t)i0*NDF + j];
        s_nf[(2*t + 1)*NDF + j] = nf_g[(size_t)i1*NDF + j];
    }
    #pragma unroll
    for (int j = 0; j < 3; j++) {
        s_ps[(2*t)*3 + j]     = pos_g[(size_t)i0*3 + j];
        s_ps[(2*t + 1)*3 + j] = pos_g[(size_t)i1*3 + j];
    }
    __syncthreads();

    float4* onf = (float4*)(out + (size_t)blockIdx.x * 512 * NDF);
    const float4* snf = (const float4*)s_nf;
    #pragma unroll
    for (int q = 0; q < 6; q++) {
        const int idx = q*256 + t;
        if (idx < 512*NDF/4) onf[idx] = snf[idx];
    }
    float4* ops = (float4*)(out + (size_t)T*NDF + (size_t)blockIdx.x * 512 * 3);
    const float4* sps = (const float4*)s_ps;
    #pragma unroll
    for (int q = 0; q < 2; q++) {
        const int idx = q*256 + t;
        if (idx < 384) ops[idx] = sps[idx];
    }
}

// ---------------------------------------------------------------------------
extern "C" void kernel_launch(void* const* d_in, const int* in_sizes, int n_in,
                              void* d_out, int out_size, void* d_ws, size_t ws_size,
                              hipStream_t stream)
{
    const float* z     = (const float*)d_in[0];
    const float* tpr   = (const float*)d_in[1];
    const int    B     = in_sizes[1];
    const int    T     = B * MAXN;

    const float* lin_w = (const float*)d_in[3];
    const float* lin_b = (const float*)d_in[4];
    const float* nn1_w = (const float*)d_in[5];
    const float* nn1_b = (const float*)d_in[6];
    const float* nn2_w = (const float*)d_in[7];
    const float* nn2_b = (const float*)d_in[8];
    const float* nd1_w = (const float*)d_in[9];
    const float* nd1_b = (const float*)d_in[10];
    const float* nd_g  = (const float*)d_in[11];
    const float* nd_be = (const float*)d_in[12];
    const float* nd_rm = (const float*)d_in[13];
    const float* nd_rv = (const float*)d_in[14];
    const float* nd2_w = (const float*)d_in[15];
    const float* nd2_b = (const float*)d_in[16];
    const float* pd1_w = (const float*)d_in[17];
    const float* pd1_b = (const float*)d_in[18];
    const float* pd_g  = (const float*)d_in[19];
    const float* pd_be = (const float*)d_in[20];
    const float* pd_rm = (const float*)d_in[21];
    const float* pd_rv = (const float*)d_in[22];
    const float* pd2_w = (const float*)d_in[23];
    const float* pd2_b = (const float*)d_in[24];
    const float* nsc   = (const float*)d_in[25];
    const float* nsh   = (const float*)d_in[26];
    const float* psc   = (const float*)d_in[27];
    const float* psh   = (const float*)d_in[28];

    float* out = (float*)d_out;

    char* wsp = (char*)d_ws;
    size_t off = 0;
    auto take = [&](size_t bytes) { void* p = wsp + off; off = (off + bytes + 255) & ~(size_t)255; return p; };

    u16*   lint  = (u16*)take(2*64*RS*sizeof(u16));          // 18432 B
    u16*   w1t3  = (u16*)take(3*2*64*RS*sizeof(u16));        // 55296 B
    u16*   w2t3  = (u16*)take(3*2*16*RS*sizeof(u16));        // 13824 B
    float* bnc   = (float*)take(256*sizeof(float));
    int*   cnt   = (int*)take(256);
    float* nf_g  = (float*)take((size_t)B*NDF*sizeof(float));
    float* pos_g = (float*)take((size_t)B*3*sizeof(float));
    int*   nn_i  = (int*)take((size_t)B*sizeof(int));
    int*   part  = (int*)take((size_t)B*sizeof(int));
    int*   bsum  = (int*)take(4096*sizeof(int));
    int*   boff  = (int*)take(4096*sizeof(int));
    int*   C     = (int*)take((size_t)B*sizeof(int));
    int*   flagged = C;   // k_fix consumes flagged BEFORE scan3 writes C

    const int nb = B / 256;

    k_prep<<<16, 256, 0, stream>>>(lin_w, nn1_w, nn2_w, nd1_w, nd2_w, pd1_w, pd2_w,
                                   nd_g, nd_be, nd_rm, nd_rv,
                                   pd_g, pd_be, pd_rm, pd_rv,
                                   lint, w1t3, w2t3, bnc, cnt);

    k_mfma<<<B/64, 256, 0, stream>>>(z, tpr, lin_b, lint, w1t3, w2t3,
                                     nn1_b, nd1_b, pd1_b, nn2_b, nd2_b, pd2_b,
                                     bnc, nsc, nsh, psc, psh,
                                     nf_g, pos_g, nn_i, out + (size_t)T*14,
                                     flagged, cnt, B);

    k_fix<<<512, 256, 0, stream>>>(z, tpr, lin_w, lin_b, nn1_w, nn1_b, nn2_w, nn2_b,
                                   flagged, cnt, nn_i, out + (size_t)T*14);

    k_scan1<<<nb, 256, 0, stream>>>(nn_i, part, bsum);
    k_scan2<<<1, nb, 0, stream>>>(bsum, boff, nb);
    k_scan3<<<nb, 256, 0, stream>>>(part, boff, C);

    k_expand<<<T/512, 256, 0, stream>>>(C, nf_g, pos_g, out, B, T);

    (void)n_in; (void)out_size; (void)ws_size;
}